// Round 1
// baseline (13257.428 us; speedup 1.0000x reference)
//
#include <hip/hip_runtime.h>
#include <hip/hip_fp16.h>
#include <hip/hip_bf16.h>

typedef __attribute__((ext_vector_type(8))) short bf16x8;
typedef __attribute__((ext_vector_type(4))) float f32x4;

__device__ __forceinline__ short f2bf(float f) {
    unsigned u = __builtin_bit_cast(unsigned, f);
    unsigned r = (u + 0x7FFFu + ((u >> 16) & 1u)) >> 16;
    return (short)r;
}

// ---------------------------------------------------------------------------
// Prep: transpose + convert weights to bf16.
// kT[n][k]  (n in 0..1535: 0..767 fwd, 768..1535 bwd), k in 0..255
// rT{f,b}[n][k] for rec_kernel (n in 0..767)
// ---------------------------------------------------------------------------
__global__ __launch_bounds__(256) void prep_kernel(
    const float* __restrict__ kf, const float* __restrict__ kb,
    const float* __restrict__ rf, const float* __restrict__ rb,
    short* __restrict__ kT, short* __restrict__ rTf, short* __restrict__ rTb)
{
    int idx = blockIdx.x * 256 + threadIdx.x;   // 0 .. 1536*256-1
    int n = idx >> 8;
    int k = idx & 255;
    const float* src = (n < 768) ? kf : kb;
    int nn = (n < 768) ? n : (n - 768);
    kT[idx] = f2bf(src[k * 768 + nn]);
    if (n < 768) {
        rTf[idx] = f2bf(rf[k * 768 + n]);
        rTb[idx] = f2bf(rb[k * 768 + n]);
    }
}

// ---------------------------------------------------------------------------
// Projection GEMM: xw[m][n] = sum_k x[m][k]*kernel[k][n] + bias0[n] (+bias1
// folded for z,r gates). M=65536, N=1536, K=256. Tile 64(M) x 128(N), 256 thr.
// Output f16 to xw_f / xw_b (layout [m][768]).
// ---------------------------------------------------------------------------
__global__ __launch_bounds__(256) void proj_kernel(
    const float* __restrict__ x, const short* __restrict__ kT,
    const float* __restrict__ bias_f, const float* __restrict__ bias_b,
    __half* __restrict__ xw_f, __half* __restrict__ xw_b)
{
    __shared__ short lA[64][264];    // x tile, bf16, padded
    __shared__ short lB[128][264];   // kernel tile (n-major), bf16, padded

    const int tid = threadIdx.x;
    const int m0 = blockIdx.x * 64;
    const int n0 = blockIdx.y * 128;

    // stage A: 64 rows x 256 f32 -> bf16
#pragma unroll
    for (int rep = 0; rep < 16; ++rep) {
        int lin = rep * 256 + tid;      // 0..4095 float4-chunks
        int r = lin >> 6;
        int c4 = lin & 63;
        float4 v = *(const float4*)(x + (size_t)(m0 + r) * 256 + c4 * 4);
        short4 s;
        s.x = f2bf(v.x); s.y = f2bf(v.y); s.z = f2bf(v.z); s.w = f2bf(v.w);
        *(short4*)&lA[r][c4 * 4] = s;
    }
    // stage B: 128 rows x 256 bf16
#pragma unroll
    for (int rep = 0; rep < 16; ++rep) {
        int lin = rep * 256 + tid;      // 0..4095 16B-chunks
        int r = lin >> 5;
        int c8 = lin & 31;
        uint4 v = *(const uint4*)(kT + (size_t)(n0 + r) * 256 + c8 * 8);
        *(uint4*)&lB[r][c8 * 8] = v;
    }
    __syncthreads();

    const int w = tid >> 6, l = tid & 63;
    const int l15 = l & 15, hi = l >> 4;

    bf16x8 a[8];
#pragma unroll
    for (int kt = 0; kt < 8; ++kt)
        a[kt] = *(const bf16x8*)&lA[w * 16 + l15][kt * 32 + hi * 8];

#pragma unroll
    for (int j = 0; j < 8; ++j) {
        f32x4 acc = {0.f, 0.f, 0.f, 0.f};
#pragma unroll
        for (int kt = 0; kt < 8; ++kt) {
            bf16x8 b = *(const bf16x8*)&lB[j * 16 + l15][kt * 32 + hi * 8];
            acc = __builtin_amdgcn_mfma_f32_16x16x32_bf16(a[kt], b, acc, 0, 0, 0);
        }
        int ng = n0 + j * 16 + l15;
        int dirb = ng >= 768;
        int nn = ng - (dirb ? 768 : 0);
        const float* bias = dirb ? bias_b : bias_f;
        // fold bias0 always; fold bias1 for z (0..255) and r (256..511) gates
        float badd = bias[nn] + ((nn < 512) ? bias[768 + nn] : 0.f);
        __half* xw = dirb ? xw_b : xw_f;
#pragma unroll
        for (int i = 0; i < 4; ++i) {
            int m = m0 + w * 16 + hi * 4 + i;
            xw[(size_t)m * 768 + nn] = __float2half(acc[i] + badd);
        }
    }
}

// ---------------------------------------------------------------------------
// Recurrence: 8 blocks (dir in {0,1} x 4 groups of 16 batch rows), 1024 thr.
// Wave w owns h columns [16w,16w+16). Per step: 24 MFMAs/wave (z,r,h tiles),
// gates lane-local in D-fragment positions, h fp32 in regs + bf16 in LDS.
// ---------------------------------------------------------------------------
__global__ __launch_bounds__(1024) void gru_kernel(
    const __half* __restrict__ xw_f, const __half* __restrict__ xw_b,
    const short* __restrict__ recT_f, const short* __restrict__ recT_b,
    const float* __restrict__ bias_f, const float* __restrict__ bias_b,
    float* __restrict__ out)
{
    __shared__ short hbf[16][264];        // h state, bf16, padded
    __shared__ __half xwl[16 * 768];      // staged xw tile for current t

    const int tid = threadIdx.x;
    const int w = tid >> 6, l = tid & 63;
    const int l15 = l & 15, hi = l >> 4;
    const int bid = blockIdx.x;
    const int dir = bid >> 2;
    const int b0 = (bid & 3) * 16;

    const __half* xw   = dir ? xw_b   : xw_f;
    const short* recT  = dir ? recT_b : recT_f;
    const float* bias  = dir ? bias_b : bias_f;

    const int cg = w * 16 + l15;                 // this lane's h column
    const float b1h = bias[768 + 512 + cg];      // recurrent bias, h-gate

    // zero h state
    for (int i = tid; i < 16 * 264; i += 1024) ((short*)hbf)[i] = 0;
    __syncthreads();

    // global_load_lds lane constants: wave w stages chunk w (1KB) and,
    // for w<8, chunk 16+w; 24 chunks of 512 halves cover the 16x768 tile.
    int hidx0 = w * 512 + l * 8;
    int r0 = hidx0 / 768, c0_ = hidx0 - r0 * 768;
    unsigned gA0 = (unsigned)(b0 + r0) * 1572864u + (unsigned)c0_ * 2u;
    int hidx1 = (16 + w) * 512 + l * 8;
    int r1 = hidx1 / 768, c1_ = hidx1 - r1 * 768;
    unsigned gA1 = (unsigned)(b0 + r1) * 1572864u + (unsigned)c1_ * 2u;

    // byte offsets of this lane's B-fragment rows (z, r, h tiles)
    unsigned offz = (((unsigned)(cg)       * 256u) + hi * 8u) * 2u;
    unsigned offr = (((unsigned)(256 + cg) * 256u) + hi * 8u) * 2u;
    unsigned offh = (((unsigned)(512 + cg) * 256u) + hi * 8u) * 2u;

    const char* recTc = (const char*)recT;
    const char* xwc   = (const char*)xw;

    f32x4 hold = {0.f, 0.f, 0.f, 0.f};

    for (int s = 0; s < 1024; ++s) {
        int t = dir ? (1023 - s) : s;

        // stage xw(t) -> LDS (latency hides under MFMA phase)
        {
            const char* g0 = xwc + gA0 + (unsigned)t * 1536u;
            __builtin_amdgcn_global_load_lds(
                (const __attribute__((address_space(1))) void*)g0,
                (__attribute__((address_space(3))) void*)((char*)xwl + w * 1024),
                16, 0, 0);
            if (w < 8) {
                const char* g1 = xwc + gA1 + (unsigned)t * 1536u;
                __builtin_amdgcn_global_load_lds(
                    (const __attribute__((address_space(1))) void*)g1,
                    (__attribute__((address_space(3))) void*)((char*)xwl + (16 + w) * 1024),
                    16, 0, 0);
            }
        }

        // MFMA phase: rec = h @ rec_kernel for this wave's 16 columns x 3 gates
        f32x4 az = {0.f,0.f,0.f,0.f}, ar = {0.f,0.f,0.f,0.f}, ah = {0.f,0.f,0.f,0.f};
        unsigned bofz = offz, bofr = offr, bofh = offh;
        asm volatile("" : "+v"(bofz), "+v"(bofr), "+v"(bofh)); // defeat cross-step load hoisting
#pragma unroll
        for (int kt = 0; kt < 8; ++kt) {
            bf16x8 aq  = *(const bf16x8*)&hbf[l15][kt * 32 + hi * 8];
            bf16x8 bz  = *(const bf16x8*)(recTc + bofz + kt * 64);
            bf16x8 br_ = *(const bf16x8*)(recTc + bofr + kt * 64);
            bf16x8 bh_ = *(const bf16x8*)(recTc + bofh + kt * 64);
            az = __builtin_amdgcn_mfma_f32_16x16x32_bf16(aq, bz,  az, 0, 0, 0);
            ar = __builtin_amdgcn_mfma_f32_16x16x32_bf16(aq, br_, ar, 0, 0, 0);
            ah = __builtin_amdgcn_mfma_f32_16x16x32_bf16(aq, bh_, ah, 0, 0, 0);
        }
        __syncthreads();   // drains vmcnt (xw staged) + all hbf reads done

        // gates (lane-local; D layout: row = 4*hi + i, col = cg)
#pragma unroll
        for (int i = 0; i < 4; ++i) {
            int ri = hi * 4 + i;
            float xz = __half2float(xwl[ri * 768 + cg]);
            float xr = __half2float(xwl[ri * 768 + 256 + cg]);
            float xh = __half2float(xwl[ri * 768 + 512 + cg]);
            float zi  = 1.f / (1.f + __expf(-(xz + az[i])));
            float rri = 1.f / (1.f + __expf(-(xr + ar[i])));
            float pre = xh + rri * (ah[i] + b1h);
            pre = fminf(fmaxf(pre, -15.f), 15.f);
            float e = __expf(2.f * pre);
            float hh = (e - 1.f) / (e + 1.f);
            float hn = zi * hold[i] + (1.f - zi) * hh;
            hold[i] = hn;
            out[(unsigned)(b0 + ri) * 524288u + (unsigned)t * 512u +
                (unsigned)dir * 256u + cg] = hn;
            hbf[ri][cg] = f2bf(hn);
        }
        __syncthreads();   // new h visible before next step's A-frag reads
    }
}

// ---------------------------------------------------------------------------
extern "C" void kernel_launch(void* const* d_in, const int* in_sizes, int n_in,
                              void* d_out, int out_size, void* d_ws, size_t ws_size,
                              hipStream_t stream) {
    const float* x   = (const float*)d_in[0];
    const float* kf  = (const float*)d_in[1];
    const float* rf  = (const float*)d_in[2];
    const float* bf_ = (const float*)d_in[3];
    const float* kb  = (const float*)d_in[4];
    const float* rb  = (const float*)d_in[5];
    const float* bb_ = (const float*)d_in[6];

    char* ws = (char*)d_ws;
    __half* xw_f = (__half*)ws;                       // 64*1024*768 f16
    __half* xw_b = (__half*)(ws + 100663296);         // same
    short* rTf   = (short*)(ws + 201326592);          // 768*256 bf16
    short* rTb   = (short*)(ws + 201719808);
    short* kT    = (short*)(ws + 202113024);          // 1536*256 bf16
    float* out   = (float*)d_out;

    hipLaunchKernelGGL(prep_kernel, dim3(1536), dim3(256), 0, stream,
                       kf, kb, rf, rb, kT, rTf, rTb);
    hipLaunchKernelGGL(proj_kernel, dim3(1024, 12), dim3(256), 0, stream,
                       x, kT, bf_, bb_, xw_f, xw_b);
    hipLaunchKernelGGL(gru_kernel, dim3(8), dim3(1024), 0, stream,
                       xw_f, xw_b, rTf, rTb, bf_, bb_, out);
}

// Round 3
// 3627.842 us; speedup vs baseline: 3.6544x; 3.6544x over previous
//
#include <hip/hip_runtime.h>
#include <hip/hip_fp16.h>
#include <hip/hip_bf16.h>

typedef __attribute__((ext_vector_type(8))) short bf16x8;
typedef __attribute__((ext_vector_type(4))) float f32x4;

__device__ __forceinline__ short f2bf(float f) {
    unsigned u = __builtin_bit_cast(unsigned, f);
    unsigned r = (u + 0x7FFFu + ((u >> 16) & 1u)) >> 16;
    return (short)r;
}

__device__ __forceinline__ float fast_rcp(float x) {
    return __builtin_amdgcn_rcpf(x);
}
__device__ __forceinline__ float fast_exp(float x) {
    // exp(x) = exp2(x * log2(e)); v_exp_f32 is the HW exp2
    return __builtin_amdgcn_exp2f(x * 1.4426950408889634f);
}

// ---------------------------------------------------------------------------
// Prep: transpose + convert weights to bf16.
// ---------------------------------------------------------------------------
__global__ __launch_bounds__(256) void prep_kernel(
    const float* __restrict__ kf, const float* __restrict__ kb,
    const float* __restrict__ rf, const float* __restrict__ rb,
    short* __restrict__ kT, short* __restrict__ rTf, short* __restrict__ rTb)
{
    int idx = blockIdx.x * 256 + threadIdx.x;   // 0 .. 1536*256-1
    int n = idx >> 8;
    int k = idx & 255;
    const float* src = (n < 768) ? kf : kb;
    int nn = (n < 768) ? n : (n - 768);
    kT[idx] = f2bf(src[k * 768 + nn]);
    if (n < 768) {
        rTf[idx] = f2bf(rf[k * 768 + n]);
        rTb[idx] = f2bf(rb[k * 768 + n]);
    }
}

// ---------------------------------------------------------------------------
// Projection GEMM: xw = x@kernel + bias0 (+bias1 folded for z,r).
// M=65536, N=1536, K=256. Tile 64x128, 256 thr. Output f16.
// ---------------------------------------------------------------------------
__global__ __launch_bounds__(256) void proj_kernel(
    const float* __restrict__ x, const short* __restrict__ kT,
    const float* __restrict__ bias_f, const float* __restrict__ bias_b,
    __half* __restrict__ xw_f, __half* __restrict__ xw_b)
{
    __shared__ short lA[64][264];
    __shared__ short lB[128][264];

    const int tid = threadIdx.x;
    const int m0 = blockIdx.x * 64;
    const int n0 = blockIdx.y * 128;

#pragma unroll
    for (int rep = 0; rep < 16; ++rep) {
        int lin = rep * 256 + tid;
        int r = lin >> 6;
        int c4 = lin & 63;
        float4 v = *(const float4*)(x + (size_t)(m0 + r) * 256 + c4 * 4);
        short4 s;
        s.x = f2bf(v.x); s.y = f2bf(v.y); s.z = f2bf(v.z); s.w = f2bf(v.w);
        *(short4*)&lA[r][c4 * 4] = s;
    }
#pragma unroll
    for (int rep = 0; rep < 16; ++rep) {
        int lin = rep * 256 + tid;
        int r = lin >> 5;
        int c8 = lin & 31;
        uint4 v = *(const uint4*)(kT + (size_t)(n0 + r) * 256 + c8 * 8);
        *(uint4*)&lB[r][c8 * 8] = v;
    }
    __syncthreads();

    const int w = tid >> 6, l = tid & 63;
    const int l15 = l & 15, hi = l >> 4;

    bf16x8 a[8];
#pragma unroll
    for (int kt = 0; kt < 8; ++kt)
        a[kt] = *(const bf16x8*)&lA[w * 16 + l15][kt * 32 + hi * 8];

#pragma unroll
    for (int j = 0; j < 8; ++j) {
        f32x4 acc = {0.f, 0.f, 0.f, 0.f};
#pragma unroll
        for (int kt = 0; kt < 8; ++kt) {
            bf16x8 b = *(const bf16x8*)&lB[j * 16 + l15][kt * 32 + hi * 8];
            acc = __builtin_amdgcn_mfma_f32_16x16x32_bf16(a[kt], b, acc, 0, 0, 0);
        }
        int ng = n0 + j * 16 + l15;
        int dirb = ng >= 768;
        int nn = ng - (dirb ? 768 : 0);
        const float* bias = dirb ? bias_b : bias_f;
        float badd = bias[nn] + ((nn < 512) ? bias[768 + nn] : 0.f);
        __half* xw = dirb ? xw_b : xw_f;
#pragma unroll
        for (int i = 0; i < 4; ++i) {
            int m = m0 + w * 16 + hi * 4 + i;
            xw[(size_t)m * 768 + nn] = __float2half(acc[i] + badd);
        }
    }
}

// ---------------------------------------------------------------------------
// Recurrence: 8 blocks (2 dirs x 4 groups of 16 batch rows), 1024 threads.
// Wave w owns h-columns [16w,16w+16). Rec-weight B-fragments held in
// REGISTERS across the whole t-loop (24 x bf16x8 = 96 VGPRs/lane); per step
// only the A-fragment (h state, bf16 in LDS) is re-read. h fp32 in regs.
// ---------------------------------------------------------------------------
__global__ __launch_bounds__(1024, 4) void gru_kernel(
    const __half* __restrict__ xw_f, const __half* __restrict__ xw_b,
    const short* __restrict__ recT_f, const short* __restrict__ recT_b,
    const float* __restrict__ bias_f, const float* __restrict__ bias_b,
    float* __restrict__ out)
{
    __shared__ short hbf[16][264];        // h state, bf16, padded
    __shared__ __half xwl[16 * 768];      // staged xw tile for current t

    const int tid = threadIdx.x;
    const int w = tid >> 6, l = tid & 63;
    const int l15 = l & 15, hi = l >> 4;
    const int bid = blockIdx.x;
    const int dir = bid >> 2;
    const int b0 = (bid & 3) * 16;

    const __half* xw   = dir ? xw_b   : xw_f;
    const short* recT  = dir ? recT_b : recT_f;
    const float* bias  = dir ? bias_b : bias_f;

    const int cg = w * 16 + l15;                 // this lane's h column
    const float b1h = bias[768 + 512 + cg];      // recurrent bias, h-gate

    // zero h state
    for (int i = tid; i < 16 * 264; i += 1024) ((short*)hbf)[i] = 0;

    // -------- hoist rec-kernel B fragments into registers (loop-invariant) --
    const char* recTc = (const char*)recT;
    unsigned offz = (((unsigned)(cg)       * 256u) + hi * 8u) * 2u;
    unsigned offr = (((unsigned)(256 + cg) * 256u) + hi * 8u) * 2u;
    unsigned offh = (((unsigned)(512 + cg) * 256u) + hi * 8u) * 2u;
    bf16x8 Bz[8], Br[8], Bh[8];
#pragma unroll
    for (int kt = 0; kt < 8; ++kt) {
        Bz[kt] = *(const bf16x8*)(recTc + offz + kt * 64);
        Br[kt] = *(const bf16x8*)(recTc + offr + kt * 64);
        Bh[kt] = *(const bf16x8*)(recTc + offh + kt * 64);
    }

    // global_load_lds lane constants: wave w stages chunk w (1KB) and,
    // for w<8, chunk 16+w; 24 chunks of 512 halves cover the 16x768 tile.
    int hidx0 = w * 512 + l * 8;
    int r0 = hidx0 / 768, c0_ = hidx0 - r0 * 768;
    unsigned gA0 = (unsigned)(b0 + r0) * 1572864u + (unsigned)c0_ * 2u;
    int hidx1 = (16 + w) * 512 + l * 8;
    int r1 = hidx1 / 768, c1_ = hidx1 - r1 * 768;
    unsigned gA1 = (unsigned)(b0 + r1) * 1572864u + (unsigned)c1_ * 2u;

    const char* xwc = (const char*)xw;

    f32x4 hold = {0.f, 0.f, 0.f, 0.f};
    __syncthreads();

    for (int s = 0; s < 1024; ++s) {
        int t = dir ? (1023 - s) : s;

        // stage xw(t) -> LDS (latency hides under MFMA phase)
        {
            const char* g0 = xwc + gA0 + (unsigned)t * 1536u;
            __builtin_amdgcn_global_load_lds(
                (const __attribute__((address_space(1))) void*)g0,
                (__attribute__((address_space(3))) void*)((char*)xwl + w * 1024),
                16, 0, 0);
            if (w < 8) {
                const char* g1 = xwc + gA1 + (unsigned)t * 1536u;
                __builtin_amdgcn_global_load_lds(
                    (const __attribute__((address_space(1))) void*)g1,
                    (__attribute__((address_space(3))) void*)((char*)xwl + (16 + w) * 1024),
                    16, 0, 0);
            }
        }

        // MFMA phase: rec = h @ rec_kernel (B in registers)
        f32x4 az = {0.f,0.f,0.f,0.f}, ar = {0.f,0.f,0.f,0.f}, ah = {0.f,0.f,0.f,0.f};
#pragma unroll
        for (int kt = 0; kt < 8; ++kt) {
            bf16x8 aq = *(const bf16x8*)&hbf[l15][kt * 32 + hi * 8];
            az = __builtin_amdgcn_mfma_f32_16x16x32_bf16(aq, Bz[kt], az, 0, 0, 0);
            ar = __builtin_amdgcn_mfma_f32_16x16x32_bf16(aq, Br[kt], ar, 0, 0, 0);
            ah = __builtin_amdgcn_mfma_f32_16x16x32_bf16(aq, Bh[kt], ah, 0, 0, 0);
        }
        __syncthreads();   // drains vmcnt (xw staged) + all hbf reads done

        // gates (lane-local; D layout: row = 4*hi + i, col = cg)
#pragma unroll
        for (int i = 0; i < 4; ++i) {
            int ri = hi * 4 + i;
            float xz = __half2float(xwl[ri * 768 + cg]);
            float xr = __half2float(xwl[ri * 768 + 256 + cg]);
            float xh = __half2float(xwl[ri * 768 + 512 + cg]);
            float zi  = fast_rcp(1.f + fast_exp(-(xz + az[i])));
            float rri = fast_rcp(1.f + fast_exp(-(xr + ar[i])));
            float pre = xh + rri * (ah[i] + b1h);
            pre = fminf(fmaxf(pre, -15.f), 15.f);
            float e = fast_exp(2.f * pre);
            float hh = (e - 1.f) * fast_rcp(e + 1.f);
            float hn = hh + zi * (hold[i] - hh);
            hold[i] = hn;
            out[(unsigned)(b0 + ri) * 524288u + (unsigned)t * 512u +
                (unsigned)dir * 256u + cg] = hn;
            hbf[ri][cg] = f2bf(hn);
        }
        __syncthreads();   // new h visible before next step's A-frag reads
    }
}

// ---------------------------------------------------------------------------
extern "C" void kernel_launch(void* const* d_in, const int* in_sizes, int n_in,
                              void* d_out, int out_size, void* d_ws, size_t ws_size,
                              hipStream_t stream) {
    const float* x   = (const float*)d_in[0];
    const float* kf  = (const float*)d_in[1];
    const float* rf  = (const float*)d_in[2];
    const float* bf_ = (const float*)d_in[3];
    const float* kb  = (const float*)d_in[4];
    const float* rb  = (const float*)d_in[5];
    const float* bb_ = (const float*)d_in[6];

    char* ws = (char*)d_ws;
    __half* xw_f = (__half*)ws;                       // 64*1024*768 f16
    __half* xw_b = (__half*)(ws + 100663296);         // same
    short* rTf   = (short*)(ws + 201326592);          // 768*256 bf16
    short* rTb   = (short*)(ws + 201719808);
    short* kT    = (short*)(ws + 202113024);          // 1536*256 bf16
    float* out   = (float*)d_out;

    hipLaunchKernelGGL(prep_kernel, dim3(1536), dim3(256), 0, stream,
                       kf, kb, rf, rb, kT, rTf, rTb);
    hipLaunchKernelGGL(proj_kernel, dim3(1024, 12), dim3(256), 0, stream,
                       x, kT, bf_, bb_, xw_f, xw_b);
    hipLaunchKernelGGL(gru_kernel, dim3(8), dim3(1024), 0, stream,
                       xw_f, xw_b, rTf, rTb, bf_, bb_, out);
}